// Round 15
// baseline (276.945 us; speedup 1.0000x reference)
//
#include <hip/hip_runtime.h>
#include <hip/hip_bf16.h>

typedef __attribute__((ext_vector_type(4)))  float f32x4;
typedef __attribute__((ext_vector_type(16))) float f32x16;
typedef __attribute__((ext_vector_type(8)))  short short8;

#define XROWS 8195            // 3 guard rows + 8192
#define XBATCH (XROWS * 1024) // elems per padded batch

__device__ __forceinline__ short f2bf(float f) {
    union { __hip_bfloat16 h; short s; } u;
    u.h = __float2bfloat16(f);
    return u.s;
}

__device__ __forceinline__ void async16(const void* g, void* l) {
    __builtin_amdgcn_global_load_lds(
        (const __attribute__((address_space(1))) unsigned int*)g,
        (__attribute__((address_space(3))) unsigned int*)l, 16, 0, 0);
}

// ---------------------------------------------------------------------------
// Prepass 1: x fp32 [4][8192][1024] -> Xbf bf16 [4][3+8192][1024], guard=0
// ---------------------------------------------------------------------------
__global__ void x_to_bf16(const float* __restrict__ x,
                          __hip_bfloat16* __restrict__ Xbf) {
    size_t idx = (size_t)blockIdx.x * blockDim.x + threadIdx.x;
    if (idx < 1536) {  // zero 4*3*1024 guard elems
        int b = (int)(idx / 384);
        int r = (int)(idx % 384);
        *reinterpret_cast<short8*>(&Xbf[(size_t)b * XBATCH + r * 8]) =
            (short8){0, 0, 0, 0, 0, 0, 0, 0};
    }
    size_t stride = (size_t)gridDim.x * blockDim.x;
    const size_t nvec = (size_t)4 * 8192 * 1024 / 8;
    for (size_t v = idx; v < nvec; v += stride) {
        size_t e = v * 8;
        int b = (int)(e >> 23);
        size_t rem = e & ((1u << 23) - 1);
        f32x4 lo = *reinterpret_cast<const f32x4*>(x + e);
        f32x4 hi = *reinterpret_cast<const f32x4*>(x + e + 4);
        short8 pk;
        pk[0] = f2bf(lo[0]); pk[1] = f2bf(lo[1]); pk[2] = f2bf(lo[2]); pk[3] = f2bf(lo[3]);
        pk[4] = f2bf(hi[0]); pk[5] = f2bf(hi[1]); pk[6] = f2bf(hi[2]); pk[7] = f2bf(hi[3]);
        *reinterpret_cast<short8*>(&Xbf[(size_t)b * XBATCH + 3 * 1024 + rem]) = pk;
    }
}

// ---------------------------------------------------------------------------
// Prepass 2: kernels [4096][1024] fp32 -> Kt [1024][4096] bf16
// ---------------------------------------------------------------------------
__global__ void kconv_transpose(const float* __restrict__ kern,
                                __hip_bfloat16* __restrict__ Kt) {
    __shared__ float tile[32][33];
    int k0 = blockIdx.x << 5;
    int f0 = blockIdx.y << 5;
    int tx = threadIdx.x & 31;
    int ty = threadIdx.x >> 5;
#pragma unroll
    for (int q = 0; q < 4; q++)
        tile[ty + q * 8][tx] = kern[(size_t)(k0 + ty + q * 8) * 1024 + f0 + tx];
    __syncthreads();
#pragma unroll
    for (int q = 0; q < 4; q++)
        Kt[((size_t)(f0 + ty + q * 8) << 12) + k0 + tx] =
            __float2bfloat16(tile[tx][ty + q * 8]);
}

// ---------------------------------------------------------------------------
// Main GEMM — 256^2, one-barrier-per-K-tile, MFMA 32x32x16:
//   8 waves (2M x 4N), wave tile 128x64. LDS 128 KiB = 2-tile dbuf x
//   (A 32KB + B 32KB). Per K-tile: vmcnt(0) [drains T's DMA, issued a
//   full phase (~3000cyc) ago - free] + 1 barrier; then 4 ks-chunks of
//   {4 A + 2 B ds_read_b128 -> 8 MFMA 32x32x16} in program order (no
//   barriers; compiler pipelines with counted lgkmcnt); stage T+1 after
//   chunk 0's reads. Depth-1 ledger race-free (R5-proven): buf[(T+1)&1]
//   written only after barrier T, when all waves' T-1 reads retired.
//   XOR swizzle byte^=((row&7)<<4) (0 conflicts R3-R14); linear DMA dest
//   + inverse-swizzled source (rule 21). 32x32 frag maps + epilogue are
//   the R11/R12-verified ones.
// ---------------------------------------------------------------------------
__global__ void __launch_bounds__(512, 2)
altconv_gemm13(const __hip_bfloat16* __restrict__ Xbf,  // [4][8195][1024]
               const __hip_bfloat16* __restrict__ Kt,   // [1024][4096]
               const float* __restrict__ biases,        // [4][1024]
               float* __restrict__ out) {               // [32768][1024]
    __shared__ alignas(16) __hip_bfloat16 LS[65536];   // 128 KiB

    // bijective XCD swizzle (512 % 8 == 0); nt fastest within an XCD chunk
    int bid  = blockIdx.x;
    int tid2 = (bid & 7) * 64 + (bid >> 3);
    int mt = tid2 >> 2;           // 0..127
    int nt = tid2 & 3;            // 0..3
    int bm0   = mt << 8;
    int batch = bm0 >> 13;
    int srow0 = bm0 & 8191;
    int bn0   = nt << 8;
    const __hip_bfloat16* xb = Xbf + (size_t)batch * XBATCH;

    int t    = threadIdx.x;
    int lane = t & 63;
    int wid  = t >> 6;            // 0..7
    int wr = wid >> 2, wc = wid & 3;
    int l31 = lane & 31, lh = lane >> 5;
    int g   = (l31 & 7) << 4;     // swizzle byte value (row&7 == l31&7)

    // 32x32x16 fragment read offsets (row pitch 64 elems = 128B):
    //   A row = wr*128 + mb*32 + l31 ; B row = wc*64 + nb*32 + l31 (+16384)
    //   col bytes = (ks*32 + lh*16) ^ g
    int aRowOff[4], bRowOff[2], ce[4];
#pragma unroll
    for (int mb = 0; mb < 4; mb++)
        aRowOff[mb] = (wr * 128 + mb * 32 + l31) * 64;
#pragma unroll
    for (int nb = 0; nb < 2; nb++)
        bRowOff[nb] = 16384 + (wc * 64 + nb * 32 + l31) * 64;
#pragma unroll
    for (int ks = 0; ks < 4; ks++)
        ce[ks] = ((ks * 32 + lh * 16) ^ g) >> 1;

    // staging precompute (R14-proven, verbatim): per thread 2 chunks/half
    int srcA[2], dstA[2], srcB[2], dstB[2];
#pragma unroll
    for (int ld = 0; ld < 2; ld++) {
        int u  = ld * 512 + t;
        int rr = u >> 3;
        int c  = u & 7;
        int growA = (rr < 64) ? rr : rr + 64;           // HF=0 quadrant rows
        dstA[ld] = growA * 8 + c;
        srcA[ld] = growA * 1024 + ((c ^ (growA & 7)) * 8);
        dstB[ld] = rr * 8 + c;
        srcB[ld] = rr * 4096 + ((c ^ (rr & 7)) * 8);
    }

    f32x16 acc[4][2];
#pragma unroll
    for (int mb = 0; mb < 4; mb++)
#pragma unroll
        for (int nb = 0; nb < 2; nb++)
#pragma unroll
            for (int r = 0; r < 16; r++) acc[mb][nb][r] = 0.f;

#define STAGEH(T, HF) do {                                                    \
        int tap_ = (T) >> 4;                                                  \
        int d0_  = ((T) & 15) << 6;                                           \
        int pA_  = ((T) & 1) << 15;  /* buf elem base: 0 or 32768 */          \
        const __hip_bfloat16* xT_ =                                           \
            xb + (size_t)(srow0 + 3 - tap_) * 1024 + d0_ + (HF) * 65536;      \
        const __hip_bfloat16* bT_ =                                           \
            Kt + (((size_t)(bn0 + (HF) * 128)) << 12) + (T) * 64;             \
        _Pragma("unroll")                                                     \
        for (int ld = 0; ld < 2; ld++)                                        \
            async16(xT_ + srcA[ld], &LS[pA_ + (dstA[ld] + (HF) * 512) * 8]);  \
        _Pragma("unroll")                                                     \
        for (int ld = 0; ld < 2; ld++)                                        \
            async16(bT_ + srcB[ld],                                           \
                    &LS[pA_ + 16384 + (dstB[ld] + (HF) * 1024) * 8]);         \
    } while (0)

    // prologue: stage tile 0 (both halves, 8 loads)
    STAGEH(0, 0);
    STAGEH(0, 1);

    for (int T = 0; T < 64; T++) {
        asm volatile("s_waitcnt vmcnt(0)" ::: "memory");   // T landed (free drain)
        __builtin_amdgcn_s_barrier();
        asm volatile("" ::: "memory");
        int base = (T & 1) << 15;
        bool dostage = (T < 63);
#pragma unroll
        for (int ks = 0; ks < 4; ks++) {
            short8 af[4], bf2[2];
#pragma unroll
            for (int mb = 0; mb < 4; mb++)
                af[mb] = *reinterpret_cast<const short8*>(
                    &LS[base + aRowOff[mb] + ce[ks]]);
#pragma unroll
            for (int nb = 0; nb < 2; nb++)
                bf2[nb] = *reinterpret_cast<const short8*>(
                    &LS[base + bRowOff[nb] + ce[ks]]);
            if (ks == 0 && dostage) { STAGEH(T + 1, 0); STAGEH(T + 1, 1); }
#pragma unroll
            for (int mb = 0; mb < 4; mb++)
#pragma unroll
                for (int nb = 0; nb < 2; nb++)
                    acc[mb][nb] = __builtin_amdgcn_mfma_f32_32x32x16_bf16(
                        af[mb], bf2[nb], acc[mb][nb], 0, 0, 0);
        }
    }

    // epilogue (R11/R12-verified): col=lane&31, row=(r&3)+8*(r>>2)+4*lh
#pragma unroll
    for (int nb = 0; nb < 2; nb++) {
        int gc = bn0 + wc * 64 + nb * 32 + l31;
        float bsum = biases[gc] + biases[1024 + gc] + biases[2048 + gc] + biases[3072 + gc];
#pragma unroll
        for (int mb = 0; mb < 4; mb++) {
            int rowb = bm0 + wr * 128 + mb * 32 + 4 * lh;
#pragma unroll
            for (int r = 0; r < 16; r++) {
                int row = rowb + (r & 3) + 8 * (r >> 2);
                out[(size_t)row * 1024 + gc] = acc[mb][nb][r] + bsum;
            }
        }
    }
#undef STAGEH
}

// ---------------------------------------------------------------------------
// Fallback: plain fp32 (no workspace needed), correct but slow
// ---------------------------------------------------------------------------
__global__ void fallback_conv(const float* __restrict__ x, const float* __restrict__ kern,
                              const float* __restrict__ biases, float* __restrict__ out) {
    __shared__ float xs[1024];
    int row = blockIdx.x;
    int f = (blockIdx.y << 8) + threadIdx.x;
    int batch = row >> 13, s = row & 8191;
    const float* xb = x + (((size_t)batch << 13) << 10);
    float acc = 0.f;
    for (int tap = 0; tap < 4; tap++) {
        int ss = s - tap;
        __syncthreads();
        for (int i = threadIdx.x; i < 1024; i += 256)
            xs[i] = (ss >= 0) ? xb[((size_t)ss << 10) + i] : 0.f;
        __syncthreads();
        const float* kp = kern + ((size_t)tap << 20) + f;
        float a = 0.f;
        for (int d = 0; d < 1024; d++) a += xs[d] * kp[(size_t)d << 10];
        acc += a + biases[(tap << 10) + f];
    }
    out[((size_t)row << 10) + f] = acc;
}

extern "C" void kernel_launch(void* const* d_in, const int* in_sizes, int n_in,
                              void* d_out, int out_size, void* d_ws, size_t ws_size,
                              hipStream_t stream) {
    const float* x      = (const float*)d_in[0];
    const float* kern   = (const float*)d_in[1];
    const float* biases = (const float*)d_in[2];
    float* out = (float*)d_out;

    const size_t xbf_bytes = (size_t)4 * XBATCH * sizeof(__hip_bfloat16); // 67.1 MB
    const size_t kt_bytes  = (size_t)4096 * 1024 * sizeof(__hip_bfloat16); // 8.4 MB

    if (ws_size >= xbf_bytes + kt_bytes) {
        __hip_bfloat16* Xbf = (__hip_bfloat16*)d_ws;
        __hip_bfloat16* Kt  = (__hip_bfloat16*)((char*)d_ws + xbf_bytes);
        x_to_bf16<<<2048, 256, 0, stream>>>(x, Xbf);
        kconv_transpose<<<dim3(128, 32), 256, 0, stream>>>(kern, Kt);
        altconv_gemm13<<<512, 512, 0, stream>>>(Xbf, Kt, biases, out);
    } else {
        fallback_conv<<<dim3(32768, 4), 256, 0, stream>>>(x, kern, biases, out);
    }
}